// Round 12
// baseline (90.364 us; speedup 1.0000x reference)
//
#include <hip/hip_runtime.h>
#include <hip/hip_bf16.h>
#include <math.h>

// Problem constants (fixed by reference setup_inputs)
#define DH 48
#define DW 48
#define DT 48
#define DC 32
#define NPOS (DH * DW * DT)

typedef float f32x2 __attribute__((ext_vector_type(2)));

// DPP quad_perm add within each 4-lane quad (VALU pipe, no LDS cost).
// 0xB1 = [1,0,3,2] (xor1), 0x4E = [2,3,0,1] (xor2).
template <int CTRL>
__device__ __forceinline__ float qperm_add(float v) {
    const int s = __builtin_amdgcn_update_dpp(
        0, __float_as_int(v), CTRL, 0xF, 0xF, true);
    return v + __int_as_float(s);
}

// 8-channel dot via packed f32x2 FMA: 4 v_pk_fma_f32 + 1 add.
__device__ __forceinline__ float dot8(const float4 a0, const float4 a1,
                                      const float4 b0, const float4 b1) {
    f32x2 acc = {0.f, 0.f};
    acc = __builtin_elementwise_fma((f32x2){a0.x, a0.y}, (f32x2){b0.x, b0.y}, acc);
    acc = __builtin_elementwise_fma((f32x2){a0.z, a0.w}, (f32x2){b0.z, b0.w}, acc);
    acc = __builtin_elementwise_fma((f32x2){a1.x, a1.y}, (f32x2){b1.x, b1.y}, acc);
    acc = __builtin_elementwise_fma((f32x2){a1.z, a1.w}, (f32x2){b1.z, b1.w}, acc);
    return acc.x + acc.y;
}

// Thread = 2 t-adjacent positions x 8 channels (4 lanes/position).
// 864 blocks x 4 waves = 3456 waves (13.5/CU) for latency hiding.
// No LDS; branch-free clamped loads; each 4-t-line window serves both
// positions (18 lines/pos vs 27). Inline softmax without max-subtraction
// (invalid neighbor -> score 0 -> e = 1, the reference's zero-pad semantics).
__global__ __launch_bounds__(256, 4) void cotr_natt_kernel(
    const float* __restrict__ q,
    const float* __restrict__ k,
    float* __restrict__ out)
{
    const int tid = threadIdx.x;
    const int sub = tid & 3;        // channel octet 0..3
    const int col = tid >> 2;       // 0..63: position-pair column
    const int ct  = col & 3;        // t-pair within tile (t fastest: coalesce)
    const int cw  = (col >> 2) & 3; // w within tile
    const int chh = col >> 4;       // h within tile

    // Grid: 12 x 12 x 6 tiles of 4h x 4w x 8t
    const int bt = blockIdx.x % (DT / 8);
    const int bw = (blockIdx.x / (DT / 8)) % (DW / 4);
    const int bh = blockIdx.x / ((DT / 8) * (DW / 4));

    const int h = bh * 4 + chh;
    const int w = bw * 4 + cw;
    const int tb = bt * 8 + ct * 2;  // pos0 = tb, pos1 = tb+1

    const int idx0 = (h * DW + w) * DT + tb;

    // q for both positions, this lane's 8 channels
    const float4* qp = reinterpret_cast<const float4*>(q + (size_t)idx0 * DC);
    const float4 qA0 = qp[sub * 2],     qA1 = qp[sub * 2 + 1];
    const float4 qB0 = qp[8 + sub * 2], qB1 = qp[8 + sub * 2 + 1];

    // t-line clamp + validity (lines tb-1 .. tb+2)
    int ttc[4];
    float tv[4];
#pragma unroll
    for (int l = 0; l < 4; ++l) {
        const int tt = tb - 1 + l;
        ttc[l] = min(max(tt, 0), DT - 1);
        tv[l] = ((unsigned)tt < DT) ? 1.0f : 0.0f;
    }

    float s0 = 0.f, oh0 = 0.f, ow0 = 0.f, ot0 = 0.f;
    float s1 = 0.f, oh1 = 0.f, ow1 = 0.f, ot1 = 0.f;

#pragma unroll
    for (int a = 0; a < 3; ++a) {
        const int hh = h + a - 1;
        const float fa = ((unsigned)hh < DH) ? 1.0f : 0.0f;
        const int hc = min(max(hh, 0), DH - 1);
#pragma unroll
        for (int b = 0; b < 3; ++b) {
            const int ww = w + b - 1;
            const float fab = fa * (((unsigned)ww < DW) ? 1.0f : 0.0f);
            const int wc = min(max(ww, 0), DW - 1);
            const int rb = (hc * DW + wc) * DT;
#pragma unroll
            for (int l = 0; l < 4; ++l) {
                const float4* kp = reinterpret_cast<const float4*>(
                    k + (size_t)(rb + ttc[l]) * DC);
                const float4 k0 = kp[sub * 2], k1 = kp[sub * 2 + 1];
                const float sc = fab * tv[l];
                if (l <= 2) {  // pos0, c = l
                    float d = dot8(qA0, qA1, k0, k1);
                    d = qperm_add<0xB1>(d);
                    d = qperm_add<0x4E>(d);
                    const float e = __expf(d * sc);
                    s0 += e;
                    if (a == 0) oh0 -= e;
                    if (a == 2) oh0 += e;
                    if (b == 0) ow0 -= e;
                    if (b == 2) ow0 += e;
                    if (l == 0) ot0 -= e;
                    if (l == 2) ot0 += e;
                }
                if (l >= 1) {  // pos1, c = l-1
                    float d = dot8(qB0, qB1, k0, k1);
                    d = qperm_add<0xB1>(d);
                    d = qperm_add<0x4E>(d);
                    const float e = __expf(d * sc);
                    s1 += e;
                    if (a == 0) oh1 -= e;
                    if (a == 2) oh1 += e;
                    if (b == 0) ow1 -= e;
                    if (b == 2) ow1 += e;
                    if (l == 1) ot1 -= e;
                    if (l == 3) ot1 += e;
                }
            }
        }
    }

    const float i0 = 1.0f / s0;
    const float i1 = 1.0f / s1;

    // Output [B, 3, H, W, T]; lanes 0/1/2 of each quad write dh/dw/dt
    // for both positions of the pair.
    if (sub == 0) {
        out[0 * NPOS + idx0]     = oh0 * i0;
        out[0 * NPOS + idx0 + 1] = oh1 * i1;
    } else if (sub == 1) {
        out[1 * NPOS + idx0]     = ow0 * i0;
        out[1 * NPOS + idx0 + 1] = ow1 * i1;
    } else if (sub == 2) {
        out[2 * NPOS + idx0]     = ot0 * i0;
        out[2 * NPOS + idx0 + 1] = ot1 * i1;
    }
}

extern "C" void kernel_launch(void* const* d_in, const int* in_sizes, int n_in,
                              void* d_out, int out_size, void* d_ws, size_t ws_size,
                              hipStream_t stream) {
    const float* q = reinterpret_cast<const float*>(d_in[0]);
    const float* k = reinterpret_cast<const float*>(d_in[1]);
    float* out = reinterpret_cast<float*>(d_out);

    const int blocks = (DH / 4) * (DW / 4) * (DT / 8); // 12*12*6 = 864
    cotr_natt_kernel<<<blocks, 256, 0, stream>>>(q, k, out);
}

// Round 14
// 78.329 us; speedup vs baseline: 1.1536x; 1.1536x over previous
//
#include <hip/hip_runtime.h>
#include <hip/hip_bf16.h>
#include <math.h>

// Problem constants (fixed by reference setup_inputs)
#define DH 48
#define DW 48
#define DT 48
#define DC 32
#define NPOS (DH * DW * DT)

// Position tile per block and its halo
#define TH 4
#define TW 4
#define TT 4
#define LH (TH + 2)                 // 6
#define LW (TW + 2)                 // 6
#define LT (TT + 2)                 // 6
#define NLINES (LH * LW * LT)       // 216 k-lines of 128 B
#define NF4 (NLINES * 8)            // 1728 float4 staging slots
#define NTHREADS 256                // 64 positions x 4 lanes

typedef __attribute__((address_space(3))) unsigned int lds_u32_t;
typedef const __attribute__((address_space(1))) unsigned int glb_u32_t;

// quad_perm DPP add within each 4-lane quad (VALU pipe, zero LDS-pipe cost).
// 0xB1 = [1,0,3,2] (xor1), 0x4E = [2,3,0,1] (xor2).
template <int CTRL>
__device__ __forceinline__ float qperm_add(float v) {
    const int s = __builtin_amdgcn_update_dpp(
        0, __float_as_int(v), CTRL, 0xF, 0xF, true);
    return v + __int_as_float(s);
}

// Block = 4x4x4 position tile, 4 lanes/position (8 channels each).
// Halo staged via global_load_lds DMA; DPP butterfly; INLINE no-max softmax:
// e = exp(score * 0/1-validity) accumulated directly into {sum, oh, ow, ot}
// (invalid neighbor -> score 0 -> e=1, the reference's zero-pad semantics).
__global__ __launch_bounds__(NTHREADS, 5) void cotr_natt_kernel(
    const float* __restrict__ q,
    const float* __restrict__ k,
    float* __restrict__ out)
{
    __shared__ __align__(16) float kl[NF4 * 4]; // 27648 B

    // Tile origin (12x12x12 blocks)
    const int bt = blockIdx.x % (DT / TT);
    const int bw = (blockIdx.x / (DT / TT)) % (DW / TW);
    const int bh = blockIdx.x / ((DT / TT) * (DW / TW));
    const int h0 = bh * TH, w0 = bw * TW, t0 = bt * TT;

    const int tid = threadIdx.x;

    // ---- stage 216 halo lines straight into LDS (async DMA) ----
    // LDS dst linear (slot*16, lane-contiguous = HW pattern); global src
    // per-lane with clamped halo coords (always in-bounds, zeroed later).
#pragma unroll
    for (int i = 0; i < 7; ++i) {
        const int s = i * NTHREADS + tid;
        if (s < NF4) {
            const int line = s >> 3, c4 = s & 7;
            const int llt = line % LT;
            const int lhw = line / LT;
            const int llw = lhw % LW;
            const int llh = lhw / LW;
            const int hh = min(max(h0 + llh - 1, 0), DH - 1);
            const int ww = min(max(w0 + llw - 1, 0), DW - 1);
            const int tt = min(max(t0 + llt - 1, 0), DT - 1);
            const float* gp =
                k + ((size_t)(hh * DW + ww) * DT + tt) * DC + c4 * 4;
            __builtin_amdgcn_global_load_lds((glb_u32_t*)gp,
                                             (lds_u32_t*)&kl[s * 4], 16, 0, 0);
        }
    }

    // position/channel decomposition: quad = one position
    const int p = tid >> 2;    // local position 0..63
    const int sub = tid & 3;   // channel octet 0..3
    const int lt = p & 3;
    const int lw = (p >> 2) & 3;
    const int lh = p >> 4;
    const int h = h0 + lh, w = w0 + lw, t = t0 + lt;
    const int idx = (h * DW + w) * DT + t;

    // q channels [sub*8, sub*8+8): 2 float4 (overlaps the DMA)
    const float4* qp = reinterpret_cast<const float4*>(q + (size_t)idx * DC);
    const float4 qa = qp[sub * 2];
    const float4 qb = qp[sub * 2 + 1];

    // Validity scales (zero-pad semantics: invalid neighbor => score 0)
    float as_[3], bs_[3], cs_[3];
#pragma unroll
    for (int u = 0; u < 3; ++u) {
        as_[u] = ((unsigned)(h + u - 1) < DH) ? 1.0f : 0.0f;
        bs_[u] = ((unsigned)(w + u - 1) < DW) ? 1.0f : 0.0f;
        cs_[u] = ((unsigned)(t + u - 1) < DT) ? 1.0f : 0.0f;
    }

    __syncthreads();

    // ---- fused: dot -> butterfly -> exp -> accumulate (no part[] array,
    // no max pass, no second loop) ----
    float sum = 0.f, oh = 0.f, ow = 0.f, ot = 0.f;
#pragma unroll
    for (int a = 0; a < 3; ++a) {
#pragma unroll
        for (int b = 0; b < 3; ++b) {
            const float sab = as_[a] * bs_[b];
#pragma unroll
            for (int c = 0; c < 3; ++c) {
                const int line = ((lh + a) * LW + (lw + b)) * LT + (lt + c);
                const float4* kp =
                    reinterpret_cast<const float4*>(&kl[line * DC]);
                const float4 ka = kp[sub * 2];
                const float4 kb = kp[sub * 2 + 1];
                float d =
                    fmaf(qa.x, ka.x,
                    fmaf(qa.y, ka.y,
                    fmaf(qa.z, ka.z,
                    fmaf(qa.w, ka.w,
                    fmaf(qb.x, kb.x,
                    fmaf(qb.y, kb.y,
                    fmaf(qb.z, kb.z, qb.w * kb.w)))))));
                d = qperm_add<0xB1>(d);  // xor1
                d = qperm_add<0x4E>(d);  // xor2
                const float e = __expf(d * (sab * cs_[c]));
                sum += e;
                if (a == 0) oh -= e;
                if (a == 2) oh += e;
                if (b == 0) ow -= e;
                if (b == 2) ow += e;
                if (c == 0) ot -= e;
                if (c == 2) ot += e;
            }
        }
    }

    const float inv = 1.0f / sum;

    // Output layout [B, 3, H, W, T]; lanes 0/1/2 of each quad write dh/dw/dt.
    if (sub == 0)      out[0 * NPOS + idx] = oh * inv;
    else if (sub == 1) out[1 * NPOS + idx] = ow * inv;
    else if (sub == 2) out[2 * NPOS + idx] = ot * inv;
}

extern "C" void kernel_launch(void* const* d_in, const int* in_sizes, int n_in,
                              void* d_out, int out_size, void* d_ws, size_t ws_size,
                              hipStream_t stream) {
    const float* q = reinterpret_cast<const float*>(d_in[0]);
    const float* k = reinterpret_cast<const float*>(d_in[1]);
    float* out = reinterpret_cast<float*>(d_out);

    const int blocks = (DH / TH) * (DW / TW) * (DT / TT); // 12*12*12 = 1728
    cotr_natt_kernel<<<blocks, NTHREADS, 0, stream>>>(q, k, out);
}